// Round 2
// baseline (21519.748 us; speedup 1.0000x reference)
//
#include <hip/hip_runtime.h>
#include <hip/hip_bf16.h>
#include <cstddef>

// Problem constants
#define NL   4
#define BB   16     // batch
#define TT   128    // seq len (S == T)
#define HH   512    // hidden == embed
#define G4   2048   // 4*H
#define BT   2048   // B*T tokens
#define VV   32000  // vocab

// ---------------- embedding gather ----------------
__global__ __launch_bounds__(128) void embed_kern(const int* __restrict__ idx,
                                                  const float* __restrict__ emb,
                                                  float* __restrict__ out) {
  int tk = blockIdx.x;
  int row = idx[tk];
  const float4* s = (const float4*)(emb + (size_t)row * HH);
  float4* d = (float4*)(out + (size_t)tk * HH);
  d[threadIdx.x] = s[threadIdx.x];
}

// ---------------- small utility kernels ----------------
__global__ __launch_bounds__(256) void zero_kern(float* __restrict__ p, int n) {
  int i = blockIdx.x * 256 + threadIdx.x;
  if (i < n) p[i] = 0.f;
}
__global__ __launch_bounds__(256) void copy_kern(float* __restrict__ d,
                                                 const float* __restrict__ s, int n) {
  int i = blockIdx.x * 256 + threadIdx.x;
  if (i < n) d[i] = s[i];
}

// ---------------- fp32 tiled GEMM: C[M,N] = A[M,K] @ B[N,K]^T + bias[N] ----------------
#define BM 128
#define BN 64
#define BK 16
__global__ __launch_bounds__(256) void gemm_bias_kern(
    const float* __restrict__ A, const float* __restrict__ B,
    const float* __restrict__ bias, float* __restrict__ C,
    int M, int N, int K)
{
  __shared__ float As[BK][BM];
  __shared__ float Bs[BK][BN];
  const int tid = threadIdx.x;
  const int m0 = blockIdx.y * BM;
  const int n0 = blockIdx.x * BN;
  const int ty = tid >> 4;
  const int tx = tid & 15;

  float acc[8][4];
#pragma unroll
  for (int i = 0; i < 8; ++i)
#pragma unroll
    for (int j = 0; j < 4; ++j) acc[i][j] = 0.f;

  for (int k0 = 0; k0 < K; k0 += BK) {
#pragma unroll
    for (int i = 0; i < 2; ++i) {
      int f = tid * 2 + i;
      int row = f >> 2;
      int k4 = (f & 3) * 4;
      float4 v = *(const float4*)(A + (size_t)(m0 + row) * K + k0 + k4);
      As[k4 + 0][row] = v.x;
      As[k4 + 1][row] = v.y;
      As[k4 + 2][row] = v.z;
      As[k4 + 3][row] = v.w;
    }
    {
      int row = tid >> 2;
      int k4 = (tid & 3) * 4;
      float4 v = *(const float4*)(B + (size_t)(n0 + row) * K + k0 + k4);
      Bs[k4 + 0][row] = v.x;
      Bs[k4 + 1][row] = v.y;
      Bs[k4 + 2][row] = v.z;
      Bs[k4 + 3][row] = v.w;
    }
    __syncthreads();
#pragma unroll
    for (int k = 0; k < BK; ++k) {
      float4 a0 = *(const float4*)&As[k][ty * 8];
      float4 a1 = *(const float4*)&As[k][ty * 8 + 4];
      float4 bv = *(const float4*)&Bs[k][tx * 4];
      float av[8] = {a0.x, a0.y, a0.z, a0.w, a1.x, a1.y, a1.z, a1.w};
      float bb[4] = {bv.x, bv.y, bv.z, bv.w};
#pragma unroll
      for (int i = 0; i < 8; ++i)
#pragma unroll
        for (int j = 0; j < 4; ++j) acc[i][j] += av[i] * bb[j];
    }
    __syncthreads();
  }
#pragma unroll
  for (int i = 0; i < 8; ++i) {
    size_t row = (size_t)(m0 + ty * 8 + i);
#pragma unroll
    for (int j = 0; j < 4; ++j) {
      int col = n0 + tx * 4 + j;
      C[row * (size_t)N + col] = acc[i][j] + (bias ? bias[col] : 0.f);
    }
  }
}

// ---------------- persistent LSTM layer kernel ----------------
// 256 blocks x 256 threads. Block owns 2 hidden units (j0 = bid*2).
// Wave w computes gate g=w for both units, all 16 batches.
// Lane layout: b4 = lane&3, ks = lane>>2 (16 k-slices, k-interleaved stride 64).
// Whh fragment in registers (64 floats/lane). h staged to LDS each step.
// Grid barrier: 8 padded atomic counters, monotonic targets.
#define HPAD 516
__global__ __launch_bounds__(256) void lstm_layer_persist(
    const float* __restrict__ xW,     // [BT,G4] bias folded
    const float* __restrict__ Whh,    // [G4,HH]
    const float* __restrict__ c_init, // [BB,HH] or nullptr (zeros)
    float* __restrict__ h0,           // [BB,HH] pre-staged initial h (step-even in)
    float* __restrict__ h1,           // [BB,HH]
    float* __restrict__ hs_out,       // [BB,TT,HH]
    float* __restrict__ fin_h,        // encoder: write final h here (or null)
    float* __restrict__ fin_c,        // encoder: write final c here (or null)
    unsigned* __restrict__ bar,       // 8 counters, stride 16 u32
    unsigned step_base)
{
  const int tid  = threadIdx.x;
  const int bid  = blockIdx.x;
  const int wave = tid >> 6;          // 0..3 == gate
  const int lane = tid & 63;
  const int b4   = lane & 3;
  const int ks   = lane >> 2;         // 0..15
  const int j0   = bid * 2;
  const int col0 = wave * HH + j0;

  __shared__ float sh[BB * HPAD];     // staged h_in
  __shared__ float gl[4][2][16];      // gates[g][u][b]
  __shared__ float cl[2][16];         // cell state [u][b]

  // ---- load weight fragment: wv[c][j] = Whh[col0+c][4*ks + 64*j .. +3]
  float4 wv[2][8];
#pragma unroll
  for (int c = 0; c < 2; ++c)
#pragma unroll
    for (int j = 0; j < 8; ++j)
      wv[c][j] = *(const float4*)(Whh + (size_t)(col0 + c) * HH + 4 * ks + 64 * j);

  // ---- init cell state
  if (tid < 32) {
    int u = tid >> 4, b = tid & 15;
    cl[u][b] = c_init ? c_init[b * HH + j0 + u] : 0.f;
  }
  __syncthreads();

  for (int t = 0; t < TT; ++t) {
    const float* hin = (t & 1) ? h1 : h0;
    float*       hout = (t & 1) ? h0 : h1;

    // stage h_in [16][512] -> LDS (2048 float4 / 256 threads = 8 each)
#pragma unroll
    for (int i = 0; i < 8; ++i) {
      int f = tid + 256 * i;
      int row = f >> 7;
      int c4 = (f & 127) << 2;
      *(float4*)&sh[row * HPAD + c4] = *(const float4*)(hin + (size_t)row * HH + c4);
    }

    // init accumulators with xW (only ks==0 lanes so it's counted once)
    float acc[2][4];
#pragma unroll
    for (int c = 0; c < 2; ++c)
#pragma unroll
      for (int i = 0; i < 4; ++i) acc[c][i] = 0.f;
    if (ks == 0) {
#pragma unroll
      for (int i = 0; i < 4; ++i) {
        int b = b4 + 4 * i;
        const float* xwp = xW + (size_t)(b * TT + t) * G4 + col0;
        acc[0][i] = xwp[0];
        acc[1][i] = xwp[1];
      }
    }
    __syncthreads();

    // dot: k in {4*ks + 64*j + m}
#pragma unroll
    for (int j = 0; j < 8; ++j) {
      int kb = 4 * ks + 64 * j;
      float4 h4[4];
#pragma unroll
      for (int i = 0; i < 4; ++i)
        h4[i] = *(const float4*)&sh[(b4 + 4 * i) * HPAD + kb];
#pragma unroll
      for (int c = 0; c < 2; ++c)
#pragma unroll
        for (int i = 0; i < 4; ++i)
          acc[c][i] += wv[c][j].x * h4[i].x + wv[c][j].y * h4[i].y +
                       wv[c][j].z * h4[i].z + wv[c][j].w * h4[i].w;
    }

    // butterfly reduce over ks (lane bits 2..5)
#pragma unroll
    for (int off = 4; off < 64; off <<= 1) {
#pragma unroll
      for (int c = 0; c < 2; ++c)
#pragma unroll
        for (int i = 0; i < 4; ++i)
          acc[c][i] += __shfl_xor(acc[c][i], off);
    }

    // lane L (0..15) holds full sum for batch b == L at acc[c][L>>2]
    if (lane < 16) {
      int i = lane >> 2;
      gl[wave][0][lane] = acc[0][i];
      gl[wave][1][lane] = acc[1][i];
    }
    __syncthreads();

    // cell update: threads 0..31 -> (u,b)
    if (tid < 32) {
      int u = tid >> 4, b = tid & 15, j = j0 + u;
      float iv = gl[0][u][b];
      float fv = gl[1][u][b];
      float gv = gl[2][u][b];
      float ov = gl[3][u][b];
      float cv = cl[u][b];
      float si = 1.f / (1.f + expf(-iv));
      float sf = 1.f / (1.f + expf(-fv));
      float so = 1.f / (1.f + expf(-ov));
      float tg = tanhf(gv);
      float cn = sf * cv + si * tg;
      float hn = so * tanhf(cn);
      cl[u][b] = cn;
      hout[b * HH + j] = hn;
      hs_out[(size_t)(b * TT + t) * HH + j] = hn;
      if (fin_h && t == TT - 1) {
        fin_h[b * HH + j] = hn;
        fin_c[b * HH + j] = cn;
      }
    }
    __syncthreads();   // drains vmcnt: all block stores are in L2

    // grid barrier (monotonic, 8 sub-counters)
    if (wave == 0) {
      if (lane == 0) {
        __threadfence();                       // release: wb L2
        atomicAdd(&bar[(bid & 7) * 16], 1u);   // relaxed agent atomic
      }
      unsigned target = 32u * (step_base + (unsigned)t + 1u);
      if (lane < 8) {
        while (__hip_atomic_load(&bar[lane * 16], __ATOMIC_RELAXED,
                                 __HIP_MEMORY_SCOPE_AGENT) < target)
          __builtin_amdgcn_s_sleep(1);
      }
      __threadfence();                         // acquire: inv L1/L2
    }
    __syncthreads();
  }
}

// ---------------- host side ----------------
extern "C" void kernel_launch(void* const* d_in, const int* in_sizes, int n_in,
                              void* d_out, int out_size, void* d_ws, size_t ws_size,
                              hipStream_t stream) {
  const int*   src     = (const int*)d_in[0];
  const int*   tgt     = (const int*)d_in[1];
  const float* src_emb = (const float*)d_in[2];
  const float* tgt_emb = (const float*)d_in[3];
  const float* enc_Wih = (const float*)d_in[4];
  const float* enc_Whh = (const float*)d_in[5];
  const float* enc_b   = (const float*)d_in[6];
  const float* dec_Wih = (const float*)d_in[7];
  const float* dec_Whh = (const float*)d_in[8];
  const float* dec_b   = (const float*)d_in[9];
  const float* fc_W    = (const float*)d_in[10];
  const float* fc_b    = (const float*)d_in[11];
  float* out = (float*)d_out;

  float* ws = (float*)d_ws;
  unsigned* bar = (unsigned*)ws;     ws += 128;                 // 8 counters, padded
  float* srcx  = ws;                 ws += (size_t)BT * HH;
  float* tgtx  = ws;                 ws += (size_t)BT * HH;
  float* hsA   = ws;                 ws += (size_t)BT * HH;
  float* hsB   = ws;                 ws += (size_t)BT * HH;
  float* xW    = ws;                 ws += (size_t)BT * G4;
  float* hbuf0 = ws;                 ws += BB * HH;
  float* hbuf1 = ws;                 ws += BB * HH;
  float* finh  = ws;                 ws += NL * BB * HH;
  float* finc  = ws;                 ws += NL * BB * HH;

  zero_kern<<<1, 256, 0, stream>>>((float*)bar, 128);

  embed_kern<<<BT, 128, 0, stream>>>(src, src_emb, srcx);
  embed_kern<<<BT, 128, 0, stream>>>(tgt, tgt_emb, tgtx);

  const int stateN = BB * HH;
  const int stateGrid = (stateN + 255) / 256;

  const float* dec_out = nullptr;

  for (int stack = 0; stack < 2; ++stack) {
    const float* Wih  = stack ? dec_Wih : enc_Wih;
    const float* Whh  = stack ? dec_Whh : enc_Whh;
    const float* bia  = stack ? dec_b   : enc_b;
    const float* curX = stack ? tgtx    : srcx;

    for (int l = 0; l < NL; ++l) {
      float* hs_out = (l & 1) ? hsB : hsA;

      // input GEMM: xW = curX @ Wih[l]^T + b[l]
      {
        dim3 grid(G4 / BN, BT / BM);
        gemm_bias_kern<<<grid, 256, 0, stream>>>(
            curX, Wih + (size_t)l * G4 * HH, bia + (size_t)l * G4, xW,
            BT, G4, HH);
      }

      // stage initial h into hbuf0
      if (stack == 0) {
        zero_kern<<<stateGrid, 256, 0, stream>>>(hbuf0, stateN);
      } else {
        copy_kern<<<stateGrid, 256, 0, stream>>>(hbuf0, finh + (size_t)l * stateN, stateN);
      }

      const float* cinit = stack ? (finc + (size_t)l * stateN) : nullptr;
      float* fh = stack ? nullptr : (finh + (size_t)l * stateN);
      float* fc = stack ? nullptr : (finc + (size_t)l * stateN);
      unsigned step_base = (unsigned)((stack * NL + l) * TT);

      lstm_layer_persist<<<256, 256, 0, stream>>>(
          xW, Whh + (size_t)l * G4 * HH, cinit, hbuf0, hbuf1, hs_out,
          fh, fc, bar, step_base);

      curX = hs_out;
      if (stack == 1 && l == NL - 1) dec_out = hs_out;
    }
  }

  // final vocab projection
  {
    dim3 grid(VV / BN, BT / BM);
    gemm_bias_kern<<<grid, 256, 0, stream>>>(dec_out, fc_W, fc_b, out, BT, VV, HH);
  }
}